// Round 1
// baseline (7884.128 us; speedup 1.0000x reference)
//
#include <hip/hip_runtime.h>

#define NN 50000
#define DD 32

__device__ __forceinline__ float lrelu(float x) { return fmaxf(x, 0.01f * x); }

__device__ __forceinline__ void lds_copy(float* dst, const float* __restrict__ src, int n) {
    for (int i = threadIdx.x; i < n; i += blockDim.x) dst[i] = src[i];
}

// acc[0..31] += x[0..K) @ W[K x 32] (row-major, W in LDS, wave-uniform broadcast reads)
template <int K>
__device__ __forceinline__ void mv_acc(float acc[DD], const float* W, const float x[K]) {
#pragma unroll
    for (int k = 0; k < K; ++k) {
        float xv = x[k];
        const float4* wp = reinterpret_cast<const float4*>(W + k * DD);
#pragma unroll
        for (int j4 = 0; j4 < DD / 4; ++j4) {
            float4 w4 = wp[j4];
            acc[4 * j4 + 0] = fmaf(xv, w4.x, acc[4 * j4 + 0]);
            acc[4 * j4 + 1] = fmaf(xv, w4.y, acc[4 * j4 + 1]);
            acc[4 * j4 + 2] = fmaf(xv, w4.z, acc[4 * j4 + 2]);
            acc[4 * j4 + 3] = fmaf(xv, w4.w, acc[4 * j4 + 3]);
        }
    }
}

__device__ __forceinline__ void load_vec32(float dst[DD], const float* __restrict__ g) {
    const float4* gp = reinterpret_cast<const float4*>(g);
#pragma unroll
    for (int j4 = 0; j4 < DD / 4; ++j4) {
        float4 v = gp[j4];
        dst[4 * j4 + 0] = v.x;
        dst[4 * j4 + 1] = v.y;
        dst[4 * j4 + 2] = v.z;
        dst[4 * j4 + 3] = v.w;
    }
}

// t-MLP: out = lrelu(h @ W1 + b1) @ W2 + b2
__device__ __forceinline__ void tlayer(float out[DD], const float h[DD], const float* W1,
                                       const float* b1, const float* W2, const float* b2) {
    float acc[DD];
#pragma unroll
    for (int j = 0; j < DD; ++j) acc[j] = b1[j];
    mv_acc<DD>(acc, W1, h);
    float m[DD];
#pragma unroll
    for (int j = 0; j < DD; ++j) m[j] = lrelu(acc[j]);
#pragma unroll
    for (int j = 0; j < DD; ++j) out[j] = b2[j];
    mv_acc<DD>(out, W2, m);
}

// u-MLP: out = lrelu(concat(h, sg) @ W1 + b1) @ W2 + b2   (W1 is 64x32)
__device__ __forceinline__ void ulayer(float out[DD], const float h[DD], const float sg[DD],
                                       const float* W1, const float* b1, const float* W2,
                                       const float* b2) {
    float acc[DD];
#pragma unroll
    for (int j = 0; j < DD; ++j) acc[j] = b1[j];
    mv_acc<DD>(acc, W1, h);
    mv_acc<DD>(acc, W1 + DD * DD, sg);
    float m[DD];
#pragma unroll
    for (int j = 0; j < DD; ++j) m[j] = lrelu(acc[j]);
#pragma unroll
    for (int j = 0; j < DD; ++j) out[j] = b2[j];
    mv_acc<DD>(out, W2, m);
}

// ---------------- Kernel 1: h0 -> t0 -> atomic scatter into s0 ----------------
__global__ __launch_bounds__(256) void k_layer0(
    const float* __restrict__ ea, const int* __restrict__ ei, const float* __restrict__ w_in,
    const float* __restrict__ b_in, const float* __restrict__ tw1, const float* __restrict__ tb1,
    const float* __restrict__ tw2, const float* __restrict__ tb2, float* __restrict__ s0, int nE) {
    __shared__ __align__(16) float lds[2176];
    float* Lwin = lds;
    float* Lbin = lds + 32;
    float* Ltw1 = lds + 64;
    float* Ltb1 = lds + 1088;
    float* Ltw2 = lds + 1120;
    float* Ltb2 = lds + 2144;
    lds_copy(Lwin, w_in, 32);
    lds_copy(Lbin, b_in, 32);
    lds_copy(Ltw1, tw1, 1024);
    lds_copy(Ltb1, tb1, 32);
    lds_copy(Ltw2, tw2, 1024);
    lds_copy(Ltb2, tb2, 32);
    __syncthreads();
    int e = blockIdx.x * 256 + threadIdx.x;
    if (e >= nE) return;
    float a = ea[e];
    float h0[DD];
#pragma unroll
    for (int j = 0; j < DD; ++j) h0[j] = fmaf(a, Lwin[j], Lbin[j]);
    float t[DD];
    tlayer(t, h0, Ltw1, Ltb1, Ltw2, Ltb2);
    int src = ei[e];
    float* sp = s0 + (size_t)src * DD;
#pragma unroll
    for (int j = 0; j < DD; ++j) atomicAdd(sp + j, t[j]);
}

// ------- Kernel 2: recompute h0, gather s0, u0 -> h1, t1 -> scatter s1 -------
__global__ __launch_bounds__(256) void k_layer1(
    const float* __restrict__ ea, const int* __restrict__ ei, const float* __restrict__ w_in,
    const float* __restrict__ b_in, const float* __restrict__ uw1, const float* __restrict__ ub1,
    const float* __restrict__ uw2, const float* __restrict__ ub2, const float* __restrict__ tw1b,
    const float* __restrict__ tb1b, const float* __restrict__ tw2b, const float* __restrict__ tb2b,
    const float* __restrict__ s0, float* __restrict__ s1, int nE) {
    __shared__ __align__(16) float lds[5312];
    float* Lwin = lds;           // 32
    float* Lbin = lds + 32;      // 32
    float* Luw1 = lds + 64;      // 2048
    float* Lub1 = lds + 2112;    // 32
    float* Luw2 = lds + 2144;    // 1024
    float* Lub2 = lds + 3168;    // 32
    float* Ltw1 = lds + 3200;    // 1024
    float* Ltb1 = lds + 4224;    // 32
    float* Ltw2 = lds + 4256;    // 1024
    float* Ltb2 = lds + 5280;    // 32
    lds_copy(Lwin, w_in, 32);
    lds_copy(Lbin, b_in, 32);
    lds_copy(Luw1, uw1, 2048);
    lds_copy(Lub1, ub1, 32);
    lds_copy(Luw2, uw2, 1024);
    lds_copy(Lub2, ub2, 32);
    lds_copy(Ltw1, tw1b, 1024);
    lds_copy(Ltb1, tb1b, 32);
    lds_copy(Ltw2, tw2b, 1024);
    lds_copy(Ltb2, tb2b, 32);
    __syncthreads();
    int e = blockIdx.x * 256 + threadIdx.x;
    if (e >= nE) return;
    float a = ea[e];
    int src = ei[e];
    float h0[DD];
#pragma unroll
    for (int j = 0; j < DD; ++j) h0[j] = fmaf(a, Lwin[j], Lbin[j]);
    float sg[DD];
    load_vec32(sg, s0 + (size_t)src * DD);
    float h1[DD];
    ulayer(h1, h0, sg, Luw1, Lub1, Luw2, Lub2);
    float t[DD];
    tlayer(t, h1, Ltw1, Ltb1, Ltw2, Ltb2);
    float* sp = s1 + (size_t)src * DD;
#pragma unroll
    for (int j = 0; j < DD; ++j) atomicAdd(sp + j, t[j]);
}

// -- Kernel 3: recompute h0,h1; gather s1 -> h2; head MLP -> exp(v); scatter denom --
__global__ __launch_bounds__(256) void k_head(
    const float* __restrict__ ea, const int* __restrict__ ei, const float* __restrict__ w_in,
    const float* __restrict__ b_in, const float* __restrict__ uw1a, const float* __restrict__ ub1a,
    const float* __restrict__ uw2a, const float* __restrict__ ub2a, const float* __restrict__ uw1b,
    const float* __restrict__ ub1b, const float* __restrict__ uw2b, const float* __restrict__ ub2b,
    const float* __restrict__ hw1, const float* __restrict__ hb1, const float* __restrict__ hw2,
    const float* __restrict__ hb2, const float* __restrict__ hw3, const float* __restrict__ hb3,
    const float* __restrict__ s0, const float* __restrict__ s1, float* __restrict__ ev,
    float* __restrict__ denom, int nE) {
    __shared__ __align__(16) float lds[9508];
    float* Lwin = lds;            // 32
    float* Lbin = lds + 32;       // 32
    float* Luw1a = lds + 64;      // 2048
    float* Lub1a = lds + 2112;    // 32
    float* Luw2a = lds + 2144;    // 1024
    float* Lub2a = lds + 3168;    // 32
    float* Luw1b = lds + 3200;    // 2048
    float* Lub1b = lds + 5248;    // 32
    float* Luw2b = lds + 5280;    // 1024
    float* Lub2b = lds + 6304;    // 32
    float* Lhw1 = lds + 6336;     // 2048
    float* Lhb1 = lds + 8384;     // 32
    float* Lhw2 = lds + 8416;     // 1024
    float* Lhb2 = lds + 9440;     // 32
    float* Lhw3 = lds + 9472;     // 32
    float* Lhb3 = lds + 9504;     // 1
    lds_copy(Lwin, w_in, 32);
    lds_copy(Lbin, b_in, 32);
    lds_copy(Luw1a, uw1a, 2048);
    lds_copy(Lub1a, ub1a, 32);
    lds_copy(Luw2a, uw2a, 1024);
    lds_copy(Lub2a, ub2a, 32);
    lds_copy(Luw1b, uw1b, 2048);
    lds_copy(Lub1b, ub1b, 32);
    lds_copy(Luw2b, uw2b, 1024);
    lds_copy(Lub2b, ub2b, 32);
    lds_copy(Lhw1, hw1, 2048);
    lds_copy(Lhb1, hb1, 32);
    lds_copy(Lhw2, hw2, 1024);
    lds_copy(Lhb2, hb2, 32);
    lds_copy(Lhw3, hw3, 32);
    lds_copy(Lhb3, hb3, 1);
    __syncthreads();
    int e = blockIdx.x * 256 + threadIdx.x;
    if (e >= nE) return;
    float a = ea[e];
    int src = ei[e];
    float h0[DD];
#pragma unroll
    for (int j = 0; j < DD; ++j) h0[j] = fmaf(a, Lwin[j], Lbin[j]);
    float sg[DD];
    load_vec32(sg, s0 + (size_t)src * DD);
    float h1[DD];
    ulayer(h1, h0, sg, Luw1a, Lub1a, Luw2a, Lub2a);
    load_vec32(sg, s1 + (size_t)src * DD);
    float h2[DD];
    ulayer(h2, h1, sg, Luw1b, Lub1b, Luw2b, Lub2b);
    // head: hcat = [h0, h2]
    float acc[DD];
#pragma unroll
    for (int j = 0; j < DD; ++j) acc[j] = Lhb1[j];
    mv_acc<DD>(acc, Lhw1, h0);
    mv_acc<DD>(acc, Lhw1 + DD * DD, h2);
    float v1[DD];
#pragma unroll
    for (int j = 0; j < DD; ++j) v1[j] = lrelu(acc[j]);
#pragma unroll
    for (int j = 0; j < DD; ++j) acc[j] = Lhb2[j];
    mv_acc<DD>(acc, Lhw2, v1);
    float val = Lhb3[0];
#pragma unroll
    for (int k = 0; k < DD; ++k) val = fmaf(lrelu(acc[k]), Lhw3[k], val);
    // softmax without max-shift (values are O(1); exactly equivalent math)
    float evv = __expf(val);
    ev[e] = evv;
    atomicAdd(denom + src, evv);
}

// ---------------- Kernel 4: normalize ----------------
__global__ __launch_bounds__(256) void k_norm(const float* __restrict__ ev,
                                              const float* __restrict__ denom,
                                              const int* __restrict__ ei, float* __restrict__ out,
                                              int nE) {
    int e = blockIdx.x * 256 + threadIdx.x;
    if (e < nE) out[e] = ev[e] / denom[ei[e]];
}

extern "C" void kernel_launch(void* const* d_in, const int* in_sizes, int n_in, void* d_out,
                              int out_size, void* d_ws, size_t ws_size, hipStream_t stream) {
    const float* ea = (const float*)d_in[0];
    const int* ei = (const int*)d_in[1];  // row 0 = source index
    const float* w_in = (const float*)d_in[2];
    const float* b_in = (const float*)d_in[3];
    const float* tw1 = (const float*)d_in[4];
    const float* tb1 = (const float*)d_in[5];
    const float* tw2 = (const float*)d_in[6];
    const float* tb2 = (const float*)d_in[7];
    const float* uw1 = (const float*)d_in[8];
    const float* ub1 = (const float*)d_in[9];
    const float* uw2 = (const float*)d_in[10];
    const float* ub2 = (const float*)d_in[11];
    const float* hw1 = (const float*)d_in[12];
    const float* hb1 = (const float*)d_in[13];
    const float* hw2 = (const float*)d_in[14];
    const float* hb2 = (const float*)d_in[15];
    const float* hw3 = (const float*)d_in[16];
    const float* hb3 = (const float*)d_in[17];

    const int nE = in_sizes[0];  // 2,000,000

    float* ws = (float*)d_ws;
    float* s0 = ws;                         // NN*DD
    float* s1 = s0 + (size_t)NN * DD;       // NN*DD
    float* denom = s1 + (size_t)NN * DD;    // NN
    float* ev = denom + NN;                 // nE

    // zero the accumulators (s0, s1, denom)
    hipMemsetAsync(ws, 0, ((size_t)2 * NN * DD + NN) * sizeof(float), stream);

    int grid = (nE + 255) / 256;
    k_layer0<<<grid, 256, 0, stream>>>(ea, ei, w_in, b_in, tw1, tb1, tw2, tb2, s0, nE);
    k_layer1<<<grid, 256, 0, stream>>>(ea, ei, w_in, b_in, uw1, ub1, uw2, ub2, tw1 + 1024,
                                       tb1 + 32, tw2 + 1024, tb2 + 32, s0, s1, nE);
    k_head<<<grid, 256, 0, stream>>>(ea, ei, w_in, b_in, uw1, ub1, uw2, ub2, uw1 + 2048, ub1 + 32,
                                     uw2 + 1024, ub2 + 32, hw1, hb1, hw2, hb2, hw3, hb3, s0, s1, ev,
                                     denom, nE);
    k_norm<<<grid, 256, 0, stream>>>(ev, denom, ei, (float*)d_out, nE);
}